// Round 1
// baseline (146.342 us; speedup 1.0000x reference)
//
#include <hip/hip_runtime.h>
#include <stdint.h>

#define BSZ 2
#define SEQ 2048
#define NHEADS 16
#define HDIM 64
#define EMBED (NHEADS * HDIM)
#define SCALE 0.125f

typedef unsigned short u16;
typedef __attribute__((ext_vector_type(8))) short bf16x8;
typedef __attribute__((ext_vector_type(4))) float f32x4;

#define LDS_STRIDE 72  // 64 + 8 pad: 144B rows -> 16B aligned, 2-way bank alias (free)

__device__ __forceinline__ u16 f2bf(float x) {
  union { float f; uint32_t u; } v;
  v.f = x;
  uint32_t r = v.u + 0x7fffu + ((v.u >> 16) & 1u);  // round-to-nearest-even
  return (u16)(r >> 16);
}

// Stage a 64x64 fp32 tile (global row-major, row stride EMBED) into bf16 LDS [64][72].
// Coalesced: per instruction the wave reads 4 full 256B rows.
__device__ __forceinline__ void stage_tile(const float* __restrict__ g,
                                           u16 (*lds)[LDS_STRIDE], float scale) {
  const int t = threadIdx.x;
#pragma unroll
  for (int it = 0; it < 4; ++it) {
    const int flat = it * 1024 + t * 4;
    const int row = flat >> 6;
    const int col = flat & 63;
    const float4 f = *reinterpret_cast<const float4*>(g + (size_t)row * EMBED + col);
    ushort4 hv;
    hv.x = f2bf(f.x * scale);
    hv.y = f2bf(f.y * scale);
    hv.z = f2bf(f.z * scale);
    hv.w = f2bf(f.w * scale);
    *reinterpret_cast<ushort4*>(&lds[row][col]) = hv;
  }
}

// Stage a 64x64 fp32 V tile TRANSPOSED into bf16 LDS Vt[d][kv].
// 4x4 register-block transpose: coalesced global reads, packed b64 LDS writes.
__device__ __forceinline__ void stage_vT(const float* __restrict__ g,
                                         u16 (*lds)[LDS_STRIDE]) {
  const int t = threadIdx.x;
  const int d0 = (t & 15) * 4;
  const int kv0 = (t >> 4) * 4;
  float a[4][4];
#pragma unroll
  for (int j = 0; j < 4; ++j)
    *reinterpret_cast<float4*>(a[j]) =
        *reinterpret_cast<const float4*>(g + (size_t)(kv0 + j) * EMBED + d0);
#pragma unroll
  for (int jj = 0; jj < 4; ++jj) {
    ushort4 hv;
    hv.x = f2bf(a[0][jj]);
    hv.y = f2bf(a[1][jj]);
    hv.z = f2bf(a[2][jj]);
    hv.w = f2bf(a[3][jj]);
    *reinterpret_cast<ushort4*>(&lds[d0 + jj][kv0]) = hv;
  }
}

__global__ __launch_bounds__(256) void mha_fwd(const float* __restrict__ Q,
                                               const float* __restrict__ K,
                                               const float* __restrict__ V,
                                               float* __restrict__ O) {
  __shared__ u16 Ks[64][LDS_STRIDE];
  __shared__ u16 Vt[64][LDS_STRIDE];
  __shared__ u16 QPs[64][LDS_STRIDE];  // Q during prologue, then reused for P

  const int qt = blockIdx.x;      // q tile: 0..31
  const int bh = blockIdx.y;      // 0..31
  const int b = bh >> 4;
  const int h = bh & 15;
  const int q_base = qt * 64;

  const float* qg = Q + ((size_t)b * SEQ + q_base) * EMBED + h * HDIM;
  const float* kg = K + (size_t)b * SEQ * EMBED + h * HDIM;
  const float* vg = V + (size_t)b * SEQ * EMBED + h * HDIM;

  stage_tile(qg, QPs, SCALE);
  __syncthreads();

  const int wave = threadIdx.x >> 6;
  const int lane = threadIdx.x & 63;
  const int fr = lane & 15;          // A-frag row / B-frag col / C-frag col
  const int fk = (lane >> 4) * 8;    // frag k offset
  const int crow = (lane >> 4) * 4;  // C-frag row base

  // Hoist Q fragments (constant across kv loop); frees QPs for P.
  const bf16x8 qf0 = *reinterpret_cast<const bf16x8*>(&QPs[wave * 16 + fr][fk]);
  const bf16x8 qf1 = *reinterpret_cast<const bf16x8*>(&QPs[wave * 16 + fr][32 + fk]);

  const f32x4 fzero = {0.f, 0.f, 0.f, 0.f};
  f32x4 oacc[4];
  float m_run[4], l_run[4];
#pragma unroll
  for (int i = 0; i < 4; ++i) {
    oacc[i] = fzero;
    m_run[i] = -3.0e38f;
    l_run[i] = 0.f;
  }

  for (int kt = 0; kt <= qt; ++kt) {
    const size_t kv_off = (size_t)(kt * 64) * EMBED;
    __syncthreads();  // all waves done reading previous Ks/Vt
    stage_tile(kg + kv_off, Ks, 1.0f);
    stage_vT(vg + kv_off, Vt);
    __syncthreads();

    // S = Q K^T : per-wave 16 q-rows x 64 keys
    f32x4 s[4];
#pragma unroll
    for (int n = 0; n < 4; ++n) {
      const bf16x8 kf0 = *reinterpret_cast<const bf16x8*>(&Ks[n * 16 + fr][fk]);
      const bf16x8 kf1 = *reinterpret_cast<const bf16x8*>(&Ks[n * 16 + fr][32 + fk]);
      s[n] = fzero;
      s[n] = __builtin_amdgcn_mfma_f32_16x16x32_bf16(qf0, kf0, s[n], 0, 0, 0);
      s[n] = __builtin_amdgcn_mfma_f32_16x16x32_bf16(qf1, kf1, s[n], 0, 0, 0);
    }

    if (kt == qt) {  // causal mask on the diagonal tile only
#pragma unroll
      for (int n = 0; n < 4; ++n)
#pragma unroll
        for (int r = 0; r < 4; ++r)
          if (n * 16 + fr > wave * 16 + crow + r) s[n][r] = -1.0e30f;
    }

    // ---- online softmax over this tile's 64 keys ----
    float tmax[4];
#pragma unroll
    for (int r = 0; r < 4; ++r)
      tmax[r] = fmaxf(fmaxf(s[0][r], s[1][r]), fmaxf(s[2][r], s[3][r]));
#pragma unroll
    for (int d = 1; d < 16; d <<= 1)
#pragma unroll
      for (int r = 0; r < 4; ++r)
        tmax[r] = fmaxf(tmax[r], __shfl_xor(tmax[r], d, 64));

    float mn[4], alpha[4], rsum[4];
#pragma unroll
    for (int r = 0; r < 4; ++r) {
      mn[r] = fmaxf(m_run[r], tmax[r]);
      alpha[r] = __expf(m_run[r] - mn[r]);
      m_run[r] = mn[r];
      rsum[r] = 0.f;
    }

    // P = exp(S - m), write bf16 P to wave-private LDS rows (no barrier needed)
#pragma unroll
    for (int n = 0; n < 4; ++n)
#pragma unroll
      for (int r = 0; r < 4; ++r) {
        const float p = __expf(s[n][r] - mn[r]);
        rsum[r] += p;
        QPs[wave * 16 + crow + r][n * 16 + fr] = f2bf(p);
      }

#pragma unroll
    for (int d = 1; d < 16; d <<= 1)
#pragma unroll
      for (int r = 0; r < 4; ++r)
        rsum[r] += __shfl_xor(rsum[r], d, 64);

#pragma unroll
    for (int r = 0; r < 4; ++r)
      l_run[r] = l_run[r] * alpha[r] + rsum[r];

#pragma unroll
    for (int nd = 0; nd < 4; ++nd)
#pragma unroll
      for (int r = 0; r < 4; ++r)
        oacc[nd][r] *= alpha[r];

    // ---- O += P V ----
#pragma unroll
    for (int kk = 0; kk < 2; ++kk) {
      const bf16x8 pf =
          *reinterpret_cast<const bf16x8*>(&QPs[wave * 16 + fr][kk * 32 + fk]);
#pragma unroll
      for (int nd = 0; nd < 4; ++nd) {
        const bf16x8 vf =
            *reinterpret_cast<const bf16x8*>(&Vt[nd * 16 + fr][kk * 32 + fk]);
        oacc[nd] = __builtin_amdgcn_mfma_f32_16x16x32_bf16(pf, vf, oacc[nd], 0, 0, 0);
      }
    }
  }

  // ---- epilogue: O / l ----
  float inv_l[4];
#pragma unroll
  for (int r = 0; r < 4; ++r) inv_l[r] = 1.0f / l_run[r];

  float* outg = O + ((size_t)b * SEQ + q_base + wave * 16) * EMBED + h * HDIM;
#pragma unroll
  for (int nd = 0; nd < 4; ++nd)
#pragma unroll
    for (int r = 0; r < 4; ++r)
      outg[(size_t)(crow + r) * EMBED + nd * 16 + fr] = oacc[nd][r] * inv_l[r];
}

extern "C" void kernel_launch(void* const* d_in, const int* in_sizes, int n_in,
                              void* d_out, int out_size, void* d_ws, size_t ws_size,
                              hipStream_t stream) {
  const float* q = (const float*)d_in[0];
  const float* k = (const float*)d_in[1];
  const float* v = (const float*)d_in[2];
  // d_in[3] (causal mask) is analytically known: 0 on/below diag, -1e9 above ->
  // exp underflows to exactly 0 in fp32, so we apply causality in-kernel.
  float* o = (float*)d_out;

  dim3 grid(SEQ / 64, BSZ * NHEADS);
  mha_fwd<<<grid, dim3(256), 0, stream>>>(q, k, v, o);
}

// Round 2
// 125.711 us; speedup vs baseline: 1.1641x; 1.1641x over previous
//
#include <hip/hip_runtime.h>
#include <stdint.h>

#define BSZ 2
#define SEQ 2048
#define NHEADS 16
#define HDIM 64
#define EMBED (NHEADS * HDIM)
#define SCALE 0.125f
#define NQT (SEQ / 64)  // 32 q-tiles of 64 rows

typedef unsigned short u16;
typedef __attribute__((ext_vector_type(8))) short bf16x8;
typedef __attribute__((ext_vector_type(4))) float f32x4;

#define LDS_STRIDE 72  // 64 + 8 pad: 144B rows -> 16B aligned, 2-way bank alias (free)

__device__ __forceinline__ u16 f2bf(float x) {
  union { float f; uint32_t u; } v;
  v.f = x;
  uint32_t r = v.u + 0x7fffu + ((v.u >> 16) & 1u);  // round-to-nearest-even
  return (u16)(r >> 16);
}

// Stage a 64x64 fp32 tile (global row-major, row stride EMBED) into bf16 LDS [64][72].
__device__ __forceinline__ void stage_tile(const float* __restrict__ g,
                                           u16 (*lds)[LDS_STRIDE], float scale) {
  const int t = threadIdx.x;
#pragma unroll
  for (int it = 0; it < 4; ++it) {
    const int flat = it * 1024 + t * 4;
    const int row = flat >> 6;
    const int col = flat & 63;
    const float4 f = *reinterpret_cast<const float4*>(g + (size_t)row * EMBED + col);
    ushort4 hv;
    hv.x = f2bf(f.x * scale);
    hv.y = f2bf(f.y * scale);
    hv.z = f2bf(f.z * scale);
    hv.w = f2bf(f.w * scale);
    *reinterpret_cast<ushort4*>(&lds[row][col]) = hv;
  }
}

// Stage a 64x64 fp32 V tile TRANSPOSED into bf16 LDS Vt[d][kv] (4x4 reg-block transpose).
__device__ __forceinline__ void stage_vT(const float* __restrict__ g,
                                         u16 (*lds)[LDS_STRIDE]) {
  const int t = threadIdx.x;
  const int d0 = (t & 15) * 4;
  const int kv0 = (t >> 4) * 4;
  float a[4][4];
#pragma unroll
  for (int j = 0; j < 4; ++j)
    *reinterpret_cast<float4*>(a[j]) =
        *reinterpret_cast<const float4*>(g + (size_t)(kv0 + j) * EMBED + d0);
#pragma unroll
  for (int jj = 0; jj < 4; ++jj) {
    ushort4 hv;
    hv.x = f2bf(a[0][jj]);
    hv.y = f2bf(a[1][jj]);
    hv.z = f2bf(a[2][jj]);
    hv.w = f2bf(a[3][jj]);
    *reinterpret_cast<ushort4*>(&lds[d0 + jj][kv0]) = hv;
  }
}

// One q-tile's work for one kv tile: QK^T -> online softmax -> O += P V.
// Ps rows [wave*16, wave*16+16) are wave-private: no barriers needed here.
__device__ __forceinline__ void process_tile(const bf16x8 qf0, const bf16x8 qf1,
                                             u16 (*Ks)[LDS_STRIDE],
                                             u16 (*Vt)[LDS_STRIDE],
                                             u16 (*Ps)[LDS_STRIDE],
                                             f32x4* oacc, float* m_run, float* l_run,
                                             int wave, int fr, int fk, int crow,
                                             bool diag) {
  const f32x4 fzero = {0.f, 0.f, 0.f, 0.f};
  f32x4 s[4];
  __builtin_amdgcn_s_setprio(1);
#pragma unroll
  for (int n = 0; n < 4; ++n) {
    const bf16x8 kf0 = *reinterpret_cast<const bf16x8*>(&Ks[n * 16 + fr][fk]);
    const bf16x8 kf1 = *reinterpret_cast<const bf16x8*>(&Ks[n * 16 + fr][32 + fk]);
    s[n] = fzero;
    s[n] = __builtin_amdgcn_mfma_f32_16x16x32_bf16(qf0, kf0, s[n], 0, 0, 0);
    s[n] = __builtin_amdgcn_mfma_f32_16x16x32_bf16(qf1, kf1, s[n], 0, 0, 0);
  }
  __builtin_amdgcn_s_setprio(0);

  if (diag) {  // causal mask on the diagonal tile only
#pragma unroll
    for (int n = 0; n < 4; ++n)
#pragma unroll
      for (int r = 0; r < 4; ++r)
        if (n * 16 + fr > wave * 16 + crow + r) s[n][r] = -1.0e30f;
  }

  float tmax[4];
#pragma unroll
  for (int r = 0; r < 4; ++r)
    tmax[r] = fmaxf(fmaxf(s[0][r], s[1][r]), fmaxf(s[2][r], s[3][r]));
#pragma unroll
  for (int d = 1; d < 16; d <<= 1)
#pragma unroll
    for (int r = 0; r < 4; ++r)
      tmax[r] = fmaxf(tmax[r], __shfl_xor(tmax[r], d, 64));

  float mn[4], alpha[4], rsum[4];
#pragma unroll
  for (int r = 0; r < 4; ++r) {
    mn[r] = fmaxf(m_run[r], tmax[r]);
    alpha[r] = __expf(m_run[r] - mn[r]);
    m_run[r] = mn[r];
    rsum[r] = 0.f;
  }

#pragma unroll
  for (int n = 0; n < 4; ++n)
#pragma unroll
    for (int r = 0; r < 4; ++r) {
      const float p = __expf(s[n][r] - mn[r]);
      rsum[r] += p;
      Ps[wave * 16 + crow + r][n * 16 + fr] = f2bf(p);
    }

#pragma unroll
  for (int d = 1; d < 16; d <<= 1)
#pragma unroll
    for (int r = 0; r < 4; ++r)
      rsum[r] += __shfl_xor(rsum[r], d, 64);

#pragma unroll
  for (int r = 0; r < 4; ++r)
    l_run[r] = l_run[r] * alpha[r] + rsum[r];

#pragma unroll
  for (int nd = 0; nd < 4; ++nd)
#pragma unroll
    for (int r = 0; r < 4; ++r)
      oacc[nd][r] *= alpha[r];

  __builtin_amdgcn_s_setprio(1);
#pragma unroll
  for (int kk = 0; kk < 2; ++kk) {
    const bf16x8 pf =
        *reinterpret_cast<const bf16x8*>(&Ps[wave * 16 + fr][kk * 32 + fk]);
#pragma unroll
    for (int nd = 0; nd < 4; ++nd) {
      const bf16x8 vf =
          *reinterpret_cast<const bf16x8*>(&Vt[nd * 16 + fr][kk * 32 + fk]);
      oacc[nd] = __builtin_amdgcn_mfma_f32_16x16x32_bf16(pf, vf, oacc[nd], 0, 0, 0);
    }
  }
  __builtin_amdgcn_s_setprio(0);
}

__device__ __forceinline__ void write_out(float* __restrict__ outg, const f32x4* oacc,
                                          const float* l_run, int crow, int fr) {
#pragma unroll
  for (int nd = 0; nd < 4; ++nd)
#pragma unroll
    for (int r = 0; r < 4; ++r)
      outg[(size_t)(crow + r) * EMBED + nd * 16 + fr] = oacc[nd][r] / l_run[r];
}

// Work-balanced causal flash attention: each block owns q-tiles {i, NQT-1-i} of
// one (b,h). Per-block MFMA work = (i+1)+(NQT-i) = NQT+1 tiles for every i.
// K/V tiles are staged once and shared by both q-tiles.
__global__ __launch_bounds__(256) void mha_fwd(const float* __restrict__ Q,
                                               const float* __restrict__ K,
                                               const float* __restrict__ V,
                                               float* __restrict__ O) {
  __shared__ u16 Ks[64][LDS_STRIDE];
  __shared__ u16 Vt[64][LDS_STRIDE];
  __shared__ u16 QPs[64][LDS_STRIDE];  // Q during prologue, then P scratch

  const int qlo = blockIdx.x;            // 0..15
  const int qhi = (NQT - 1) - blockIdx.x;  // 31..16
  const int bh = blockIdx.y;
  const int b = bh >> 4;
  const int h = bh & 15;

  const float* qg = Q + (size_t)b * SEQ * EMBED + h * HDIM;
  const float* kg = K + (size_t)b * SEQ * EMBED + h * HDIM;
  const float* vg = V + (size_t)b * SEQ * EMBED + h * HDIM;

  const int wave = threadIdx.x >> 6;
  const int lane = threadIdx.x & 63;
  const int fr = lane & 15;
  const int fk = (lane >> 4) * 8;
  const int crow = (lane >> 4) * 4;

  // Prologue: hoist Q fragments for both tiles (QPs then becomes P scratch).
  stage_tile(qg + (size_t)qlo * 64 * EMBED, QPs, SCALE);
  __syncthreads();
  const bf16x8 qlo0 = *reinterpret_cast<const bf16x8*>(&QPs[wave * 16 + fr][fk]);
  const bf16x8 qlo1 = *reinterpret_cast<const bf16x8*>(&QPs[wave * 16 + fr][32 + fk]);
  __syncthreads();
  stage_tile(qg + (size_t)qhi * 64 * EMBED, QPs, SCALE);
  __syncthreads();
  const bf16x8 qhi0 = *reinterpret_cast<const bf16x8*>(&QPs[wave * 16 + fr][fk]);
  const bf16x8 qhi1 = *reinterpret_cast<const bf16x8*>(&QPs[wave * 16 + fr][32 + fk]);

  const f32x4 fzero = {0.f, 0.f, 0.f, 0.f};
  f32x4 oacc_lo[4], oacc_hi[4];
  float m_lo[4], l_lo[4], m_hi[4], l_hi[4];
#pragma unroll
  for (int i = 0; i < 4; ++i) {
    oacc_lo[i] = fzero;
    oacc_hi[i] = fzero;
    m_lo[i] = -3.0e38f;
    l_lo[i] = 0.f;
    m_hi[i] = -3.0e38f;
    l_hi[i] = 0.f;
  }

  for (int kt = 0; kt <= qhi; ++kt) {
    const size_t kv_off = (size_t)(kt * 64) * EMBED;
    __syncthreads();  // all waves done reading previous Ks/Vt
    stage_tile(kg + kv_off, Ks, 1.0f);
    stage_vT(vg + kv_off, Vt);
    __syncthreads();

    process_tile(qhi0, qhi1, Ks, Vt, QPs, oacc_hi, m_hi, l_hi,
                 wave, fr, fk, crow, kt == qhi);
    if (kt <= qlo)
      process_tile(qlo0, qlo1, Ks, Vt, QPs, oacc_lo, m_lo, l_lo,
                   wave, fr, fk, crow, kt == qlo);
  }

  float* outg = O + ((size_t)b * SEQ + wave * 16) * EMBED + h * HDIM;
  write_out(outg + (size_t)qlo * 64 * EMBED, oacc_lo, l_lo, crow, fr);
  write_out(outg + (size_t)qhi * 64 * EMBED, oacc_hi, l_hi, crow, fr);
}

extern "C" void kernel_launch(void* const* d_in, const int* in_sizes, int n_in,
                              void* d_out, int out_size, void* d_ws, size_t ws_size,
                              hipStream_t stream) {
  const float* q = (const float*)d_in[0];
  const float* k = (const float*)d_in[1];
  const float* v = (const float*)d_in[2];
  // d_in[3] (causal mask) is analytically 0/-1e9 causal; applied in-kernel.
  float* o = (float*)d_out;

  dim3 grid(NQT / 2, BSZ * NHEADS);
  mha_fwd<<<grid, dim3(256), 0, stream>>>(q, k, v, o);
}

// Round 3
// 89.767 us; speedup vs baseline: 1.6302x; 1.4004x over previous
//
#include <hip/hip_runtime.h>
#include <stdint.h>

#define BSZ 2
#define SEQ 2048
#define NHEADS 16
#define HDIM 64
#define EMBED (NHEADS * HDIM)
#define SCALE 0.125f
#define NQT (SEQ / 64)  // 32 q-tiles of 64 rows

typedef unsigned short u16;
typedef __attribute__((ext_vector_type(8))) short bf16x8;
typedef __attribute__((ext_vector_type(4))) float f32x4;
typedef __attribute__((ext_vector_type(8))) unsigned short ushort8;

#define LDS_STRIDE 72  // 144B rows: 16B-aligned b128 frags, throughput-optimal reads

__device__ __forceinline__ u16 f2bf(float x) {
  union { float f; uint32_t u; } v;
  v.f = x;
  uint32_t r = v.u + 0x7fffu + ((v.u >> 16) & 1u);  // RNE
  return (u16)(r >> 16);
}

// ---- K/Q staging: 64x64 fp32 tile -> bf16 LDS [64][72], split load/store ----
// Each thread: 2 iters x 8 contiguous floats (32B/lane global, 16B LDS writes).
__device__ __forceinline__ void load_rows(const float* __restrict__ g, float4* r) {
  const int t = threadIdx.x;
#pragma unroll
  for (int it = 0; it < 2; ++it) {
    const int flat = it * 2048 + t * 8;
    const float* p = g + (size_t)(flat >> 6) * EMBED + (flat & 63);
    r[it * 2] = *reinterpret_cast<const float4*>(p);
    r[it * 2 + 1] = *reinterpret_cast<const float4*>(p + 4);
  }
}

__device__ __forceinline__ void store_rows(const float4* r, u16 (*lds)[LDS_STRIDE],
                                           float scale) {
  const int t = threadIdx.x;
#pragma unroll
  for (int it = 0; it < 2; ++it) {
    const int flat = it * 2048 + t * 8;
    const int row = flat >> 6;
    const int col = flat & 63;
    const float4 a = r[it * 2], b = r[it * 2 + 1];
    ushort8 hv;
    hv[0] = f2bf(a.x * scale); hv[1] = f2bf(a.y * scale);
    hv[2] = f2bf(a.z * scale); hv[3] = f2bf(a.w * scale);
    hv[4] = f2bf(b.x * scale); hv[5] = f2bf(b.y * scale);
    hv[6] = f2bf(b.z * scale); hv[7] = f2bf(b.w * scale);
    *reinterpret_cast<ushort8*>(&lds[row][col]) = hv;
  }
}

// ---- V staging: 64x64 fp32 -> transposed bf16 LDS Vt[d][kv], split ----
// kv from low lane bits / d from high bits: conflict-free LDS writes.
__device__ __forceinline__ void load_v(const float* __restrict__ g, float* a) {
  const int t = threadIdx.x;
  const int kv0 = (t & 15) * 4;
  const int d0 = (t >> 4) * 4;
#pragma unroll
  for (int j = 0; j < 4; ++j)
    *reinterpret_cast<float4*>(a + 4 * j) =
        *reinterpret_cast<const float4*>(g + (size_t)(kv0 + j) * EMBED + d0);
}

__device__ __forceinline__ void store_vT(const float* a, u16 (*lds)[LDS_STRIDE]) {
  const int t = threadIdx.x;
  const int kv0 = (t & 15) * 4;
  const int d0 = (t >> 4) * 4;
#pragma unroll
  for (int jj = 0; jj < 4; ++jj) {
    ushort4 hv;
    hv.x = f2bf(a[0 * 4 + jj]);
    hv.y = f2bf(a[1 * 4 + jj]);
    hv.z = f2bf(a[2 * 4 + jj]);
    hv.w = f2bf(a[3 * 4 + jj]);
    *reinterpret_cast<ushort4*>(&lds[d0 + jj][kv0]) = hv;
  }
}

// One q-stream's work for one kv tile. Ps rows [wave*16,+16) are wave-private.
__device__ __forceinline__ void process_tile(const bf16x8 qf0, const bf16x8 qf1,
                                             u16 (*Ks)[LDS_STRIDE],
                                             u16 (*Vt)[LDS_STRIDE],
                                             u16 (*Ps)[LDS_STRIDE],
                                             f32x4* oacc, float* m_run, float* l_run,
                                             int wave, int fr, int fk, int crow,
                                             bool diag) {
  const f32x4 fzero = {0.f, 0.f, 0.f, 0.f};
  f32x4 s[4];
  __builtin_amdgcn_s_setprio(1);
#pragma unroll
  for (int n = 0; n < 4; ++n) {
    const bf16x8 kf0 = *reinterpret_cast<const bf16x8*>(&Ks[n * 16 + fr][fk]);
    const bf16x8 kf1 = *reinterpret_cast<const bf16x8*>(&Ks[n * 16 + fr][32 + fk]);
    s[n] = fzero;
    s[n] = __builtin_amdgcn_mfma_f32_16x16x32_bf16(qf0, kf0, s[n], 0, 0, 0);
    s[n] = __builtin_amdgcn_mfma_f32_16x16x32_bf16(qf1, kf1, s[n], 0, 0, 0);
  }
  __builtin_amdgcn_s_setprio(0);

  if (diag) {
#pragma unroll
    for (int n = 0; n < 4; ++n)
#pragma unroll
      for (int r = 0; r < 4; ++r)
        if (n * 16 + fr > wave * 16 + crow + r) s[n][r] = -1.0e30f;
  }

  float tmax[4];
#pragma unroll
  for (int r = 0; r < 4; ++r)
    tmax[r] = fmaxf(fmaxf(s[0][r], s[1][r]), fmaxf(s[2][r], s[3][r]));
#pragma unroll
  for (int d = 1; d < 16; d <<= 1)
#pragma unroll
    for (int r = 0; r < 4; ++r)
      tmax[r] = fmaxf(tmax[r], __shfl_xor(tmax[r], d, 64));

  float mn[4], alpha[4], rsum[4];
#pragma unroll
  for (int r = 0; r < 4; ++r) {
    mn[r] = fmaxf(m_run[r], tmax[r]);
    alpha[r] = __expf(m_run[r] - mn[r]);
    m_run[r] = mn[r];
    rsum[r] = 0.f;
  }

#pragma unroll
  for (int n = 0; n < 4; ++n)
#pragma unroll
    for (int r = 0; r < 4; ++r) {
      const float p = __expf(s[n][r] - mn[r]);
      rsum[r] += p;
      Ps[wave * 16 + crow + r][n * 16 + fr] = f2bf(p);
    }

#pragma unroll
  for (int d = 1; d < 16; d <<= 1)
#pragma unroll
    for (int r = 0; r < 4; ++r)
      rsum[r] += __shfl_xor(rsum[r], d, 64);

#pragma unroll
  for (int r = 0; r < 4; ++r)
    l_run[r] = l_run[r] * alpha[r] + rsum[r];

#pragma unroll
  for (int nd = 0; nd < 4; ++nd)
#pragma unroll
    for (int r = 0; r < 4; ++r)
      oacc[nd][r] *= alpha[r];

  __builtin_amdgcn_s_setprio(1);
#pragma unroll
  for (int kk = 0; kk < 2; ++kk) {
    const bf16x8 pf =
        *reinterpret_cast<const bf16x8*>(&Ps[wave * 16 + fr][kk * 32 + fk]);
#pragma unroll
    for (int nd = 0; nd < 4; ++nd) {
      const bf16x8 vf =
          *reinterpret_cast<const bf16x8*>(&Vt[nd * 16 + fr][kk * 32 + fk]);
      oacc[nd] = __builtin_amdgcn_mfma_f32_16x16x32_bf16(pf, vf, oacc[nd], 0, 0, 0);
    }
  }
  __builtin_amdgcn_s_setprio(0);
}

__device__ __forceinline__ void write_out(float* __restrict__ outg, const f32x4* oacc,
                                          const float* l_run, int crow, int fr) {
#pragma unroll
  for (int nd = 0; nd < 4; ++nd)
#pragma unroll
    for (int r = 0; r < 4; ++r)
      outg[(size_t)(crow + r) * EMBED + nd * 16 + fr] = oacc[nd][r] / l_run[r];
}

// Work-balanced causal flash attention with double-buffered async staging.
// Block owns q-tiles {i, NQT-1-i}: (i+1)+(NQT-i) = NQT+1 kv-steps for every i.
__global__ __launch_bounds__(256, 2) void mha_fwd(const float* __restrict__ Q,
                                                  const float* __restrict__ K,
                                                  const float* __restrict__ V,
                                                  float* __restrict__ O) {
  __shared__ u16 Ks[2][64][LDS_STRIDE];
  __shared__ u16 Vt[2][64][LDS_STRIDE];
  __shared__ u16 Ps[64][LDS_STRIDE];

  const int qlo = blockIdx.x;              // 0..15
  const int qhi = (NQT - 1) - blockIdx.x;  // 31..16
  const int bh = blockIdx.y;
  const int b = bh >> 4;
  const int h = bh & 15;

  const float* qg = Q + (size_t)b * SEQ * EMBED + h * HDIM;
  const float* kg = K + (size_t)b * SEQ * EMBED + h * HDIM;
  const float* vg = V + (size_t)b * SEQ * EMBED + h * HDIM;

  const int wave = threadIdx.x >> 6;
  const int lane = threadIdx.x & 63;
  const int fr = lane & 15;
  const int fk = (lane >> 4) * 8;
  const int crow = (lane >> 4) * 4;

  // ---- prologue: stage both Q tiles through the two K buffers ----
  {
    float4 t0[4], t1[4];
    load_rows(qg + (size_t)qlo * 64 * EMBED, t0);
    load_rows(qg + (size_t)qhi * 64 * EMBED, t1);
    store_rows(t0, Ks[0], SCALE);
    store_rows(t1, Ks[1], SCALE);
  }
  __syncthreads();
  const bf16x8 qlo0 = *reinterpret_cast<const bf16x8*>(&Ks[0][wave * 16 + fr][fk]);
  const bf16x8 qlo1 = *reinterpret_cast<const bf16x8*>(&Ks[0][wave * 16 + fr][32 + fk]);
  const bf16x8 qhi0 = *reinterpret_cast<const bf16x8*>(&Ks[1][wave * 16 + fr][fk]);
  const bf16x8 qhi1 = *reinterpret_cast<const bf16x8*>(&Ks[1][wave * 16 + fr][32 + fk]);

  // issue kv-tile 0 loads (global->reg) while Q frags settle
  float4 kr[4];
  float vr[16];
  load_rows(kg, kr);
  load_v(vg, vr);
  __syncthreads();  // everyone done reading Q from Ks[0]/Ks[1]
  store_rows(kr, Ks[0], 1.0f);
  store_vT(vr, Vt[0]);
  __syncthreads();

  const f32x4 fzero = {0.f, 0.f, 0.f, 0.f};
  f32x4 oacc_lo[4], oacc_hi[4];
  float m_lo[4], l_lo[4], m_hi[4], l_hi[4];
#pragma unroll
  for (int i = 0; i < 4; ++i) {
    oacc_lo[i] = fzero;
    oacc_hi[i] = fzero;
    m_lo[i] = -3.0e38f;
    l_lo[i] = 0.f;
    m_hi[i] = -3.0e38f;
    l_hi[i] = 0.f;
  }

  int cur = 0;
  for (int kt = 0; kt <= qhi; ++kt) {
    // prefetch next kv tile into registers (overlaps with compute below)
    if (kt < qhi) {
      const size_t kv_off = (size_t)((kt + 1) * 64) * EMBED;
      load_rows(kg + kv_off, kr);
      load_v(vg + kv_off, vr);
    }

    process_tile(qhi0, qhi1, Ks[cur], Vt[cur], Ps, oacc_hi, m_hi, l_hi,
                 wave, fr, fk, crow, kt == qhi);
    if (kt <= qlo)
      process_tile(qlo0, qlo1, Ks[cur], Vt[cur], Ps, oacc_lo, m_lo, l_lo,
                   wave, fr, fk, crow, kt == qlo);

    // write next tile into the other buffer; one barrier per iteration
    if (kt < qhi) {
      store_rows(kr, Ks[cur ^ 1], 1.0f);
      store_vT(vr, Vt[cur ^ 1]);
    }
    __syncthreads();
    cur ^= 1;
  }

  float* outg = O + ((size_t)b * SEQ + wave * 16) * EMBED + h * HDIM;
  write_out(outg + (size_t)qlo * 64 * EMBED, oacc_lo, l_lo, crow, fr);
  write_out(outg + (size_t)qhi * 64 * EMBED, oacc_hi, l_hi, crow, fr);
}

extern "C" void kernel_launch(void* const* d_in, const int* in_sizes, int n_in,
                              void* d_out, int out_size, void* d_ws, size_t ws_size,
                              hipStream_t stream) {
  const float* q = (const float*)d_in[0];
  const float* k = (const float*)d_in[1];
  const float* v = (const float*)d_in[2];
  // d_in[3] (causal mask) is analytically 0/-1e9 causal; applied in-kernel.
  float* o = (float*)d_out;

  dim3 grid(NQT / 2, BSZ * NHEADS);
  mha_fwd<<<grid, dim3(256), 0, stream>>>(q, k, v, o);
}